// Round 2
// baseline (1979.523 us; speedup 1.0000x reference)
//
#include <hip/hip_runtime.h>
#include <hip/hip_bf16.h>
#include <cstdint>

// NeighborhoodAttentionS2: B=2, C=256, H(lat)=128, W(lon)=256
// Phase 1: q/k/v = W @ query (+bias), bf16 MFMA, stored [b][h][w][c] bf16 in ws
// Phase 2: per-output-point online-softmax over CSR neighborhood, gather k/v
// ws layout: qB[32MB] | kB[32MB] | vB[32MB] | row_ptr[129 ints]

#define NLAT 128
#define NLON 256
#define NCH  256
#define HWSZ (NLAT * NLON)   // 32768

typedef __attribute__((ext_vector_type(4))) float f32x4;
typedef __attribute__((ext_vector_type(8))) short s16x8;

__device__ __forceinline__ float bf2f(unsigned int hi_bits) {
    return __uint_as_float(hi_bits);
}
__device__ __forceinline__ unsigned short f2bf(float f) {
    unsigned int u = __float_as_uint(f);
    unsigned int r = (u + 0x7fffu + ((u >> 16) & 1u)) >> 16;
    return (unsigned short)r;
}

// ---------------- CSR row pointers ----------------
__global__ void k_rowptr(const int* __restrict__ rows, int nnz, int* __restrict__ rp) {
    int ho = threadIdx.x;
    if (ho > NLAT) return;
    int lo = 0, hi = nnz;
    while (lo < hi) {
        int mid = (lo + hi) >> 1;
        if (rows[mid] < ho) lo = mid + 1; else hi = mid;
    }
    rp[ho] = lo;
}

// ---------------- QKV projection (bf16 MFMA GEMM) ----------------
// grid (1024, 3), block 256 (4 waves). Block: M=256 (out ch), N=64 points, K=256.
// Wave w owns M rows [64w, 64w+64). out[b][hw][m] = sum_c Wm[m][c]*scale*query[b][c][hw] + bias[m]
__global__ __launch_bounds__(256) void k_qkv(
    const float* __restrict__ query,
    const float* __restrict__ qw, const float* __restrict__ kw, const float* __restrict__ vw,
    const float* __restrict__ qb, const float* __restrict__ kb, const float* __restrict__ vb,
    unsigned short* __restrict__ qB, unsigned short* __restrict__ kB, unsigned short* __restrict__ vB)
{
    const int y = blockIdx.y;
    const float* Wm; const float* bias; unsigned short* outp; float scale;
    if (y == 0)      { Wm = qw; bias = qb; outp = qB; scale = 0.0625f; }  // fold 1/sqrt(C) into q_w
    else if (y == 1) { Wm = kw; bias = kb; outp = kB; scale = 1.0f; }
    else             { Wm = vw; bias = vb; outp = vB; scale = 1.0f; }

    __shared__ unsigned short As[256][40];  // [m][k], pad 32->40 (80B rows, 16B aligned)
    __shared__ unsigned short Bs[64][40];   // [n][k]

    const int n0  = blockIdx.x * 64;
    const int b   = n0 >> 15;            // HWSZ = 32768
    const int hw0 = n0 & (HWSZ - 1);
    const float* qsrc = query + (size_t)b * NCH * HWSZ + hw0;

    const int tid  = threadIdx.x;
    const int lane = tid & 63;
    const int w    = tid >> 6;

    f32x4 acc[4][4] = {};

    const int la_m = tid >> 3;        // 0..31
    const int la_k = (tid & 7) * 4;   // 0,4,..,28
    const int lb_n = tid & 63;
    const int lb_k = tid >> 6;        // 0..3

    for (int ks = 0; ks < 8; ++ks) {
        const int k0 = ks * 32;
        // stage A (weights, fp32 -> bf16, scaled)
        #pragma unroll
        for (int r = 0; r < 8; ++r) {
            const int m = la_m + r * 32;
            const float4 v = *(const float4*)(Wm + (size_t)m * NCH + k0 + la_k);
            ushort4 st;
            st.x = f2bf(v.x * scale); st.y = f2bf(v.y * scale);
            st.z = f2bf(v.z * scale); st.w = f2bf(v.w * scale);
            *(ushort4*)&As[m][la_k] = st;
        }
        // stage B (query, fp32 -> bf16, transposed to [n][k])
        #pragma unroll
        for (int r = 0; r < 8; ++r) {
            const int kk = lb_k + r * 4;
            Bs[lb_n][kk] = f2bf(qsrc[(size_t)(k0 + kk) * HWSZ + lb_n]);
        }
        __syncthreads();

        s16x8 af[4], bfr[4];
        #pragma unroll
        for (int i = 0; i < 4; ++i)
            af[i] = *(const s16x8*)&As[w * 64 + i * 16 + (lane & 15)][(lane >> 4) * 8];
        #pragma unroll
        for (int j = 0; j < 4; ++j)
            bfr[j] = *(const s16x8*)&Bs[j * 16 + (lane & 15)][(lane >> 4) * 8];
        #pragma unroll
        for (int i = 0; i < 4; ++i)
            #pragma unroll
            for (int j = 0; j < 4; ++j)
                acc[i][j] = __builtin_amdgcn_mfma_f32_16x16x32_bf16(af[i], bfr[j], acc[i][j], 0, 0, 0);
        __syncthreads();
    }

    // epilogue: D[m][n], row m = base + 4*(lane>>4)+r, col n = tile + (lane&15)
    const int mrow = (lane >> 4) * 4;
    #pragma unroll
    for (int i = 0; i < 4; ++i) {
        const int m0 = w * 64 + i * 16 + mrow;
        const float4 bv = *(const float4*)(bias + m0);
        #pragma unroll
        for (int j = 0; j < 4; ++j) {
            const int n = j * 16 + (lane & 15);
            ushort4 st;
            st.x = f2bf(acc[i][j][0] + bv.x);
            st.y = f2bf(acc[i][j][1] + bv.y);
            st.z = f2bf(acc[i][j][2] + bv.z);
            st.w = f2bf(acc[i][j][3] + bv.w);
            *(ushort4*)(outp + (((size_t)(b * HWSZ + hw0 + n)) << 8) + m0) = st;
        }
    }
}

// ---------------- neighborhood attention ----------------
// 1D grid 4096 blocks (XCD-swizzled), block 1024 = 16 waves.
// Logical block: (b, ho, 16-wide wo chunk); wave handles one wo.
__global__ __launch_bounds__(1024) void k_attn(
    const unsigned short* __restrict__ qB,
    const unsigned short* __restrict__ kB,
    const unsigned short* __restrict__ vB,
    const int* __restrict__ psi_col,
    const float* __restrict__ qwt,
    const int* __restrict__ rp,
    float* __restrict__ out)
{
    // XCD-bijective swizzle: 4096 = 8 XCD * 512; XCD k gets contiguous logical chunk
    const int bid  = blockIdx.x;
    const int orig = ((bid & 7) << 9) | (bid >> 3);
    const int wo0  = (orig & 15) * 16;
    const int ho   = (orig >> 4) & 127;
    const int b    = orig >> 11;

    const int tid  = threadIdx.x;
    const int lane = tid & 63;
    const int wv   = tid >> 6;     // 0..15
    const int wo   = wo0 + wv;

    __shared__ float sm[16][256];
    __shared__ float sml[16];

    const int start = rp[ho];
    const int end   = rp[ho + 1];

    // q: 4 channels per lane
    const uint2 qu = *(const uint2*)(qB + (((size_t)((b * NLAT + ho) * NLON + wo)) << 8) + lane * 4);
    const float q0 = bf2f(qu.x << 16);
    const float q1 = bf2f(qu.x & 0xffff0000u);
    const float q2 = bf2f(qu.y << 16);
    const float q3 = bf2f(qu.y & 0xffff0000u);

    float m_run = -3.0e38f, l_run = 0.0f;
    float a0 = 0.f, a1 = 0.f, a2 = 0.f, a3 = 0.f;

    const int bbase = b * HWSZ;

    for (int n = start; n < end; ++n) {
        const int col  = psi_col[n];                 // uniform -> s_load
        const int hi   = col >> 8;
        const int widx = (col + wo) & 255;           // (wi + wo) mod W
        const size_t off = (((size_t)(bbase + hi * NLON + widx)) << 8) + lane * 4;

        const uint2 ku = *(const uint2*)(kB + off);
        float p = bf2f(ku.x << 16) * q0;
        p = fmaf(bf2f(ku.x & 0xffff0000u), q1, p);
        p = fmaf(bf2f(ku.y << 16),         q2, p);
        p = fmaf(bf2f(ku.y & 0xffff0000u), q3, p);
        p += __shfl_xor(p, 32);
        p += __shfl_xor(p, 16);
        p += __shfl_xor(p, 8);
        p += __shfl_xor(p, 4);
        p += __shfl_xor(p, 2);
        p += __shfl_xor(p, 1);

        const float qwv = qwt[hi];
        const uint2 vu  = *(const uint2*)(vB + off);

        float alpha;
        if (p > m_run) {                 // wave-uniform branch
            const float corr = __expf(m_run - p);
            m_run = p;
            l_run *= corr; a0 *= corr; a1 *= corr; a2 *= corr; a3 *= corr;
            alpha = qwv;                 // exp(p - p) = 1
        } else {
            alpha = __expf(p - m_run) * qwv;
        }
        l_run += alpha;
        a0 = fmaf(alpha, bf2f(vu.x << 16),         a0);
        a1 = fmaf(alpha, bf2f(vu.x & 0xffff0000u), a1);
        a2 = fmaf(alpha, bf2f(vu.y << 16),         a2);
        a3 = fmaf(alpha, bf2f(vu.y & 0xffff0000u), a3);
    }

    *(float4*)&sm[wv][lane * 4] = make_float4(a0, a1, a2, a3);
    if (lane == 0) sml[wv] = 1.0f / l_run;
    __syncthreads();

    // transpose write: 4 consecutive threads cover one 64B line of out[b][c][ho][wo0..wo0+16)
    const int quarter = tid & 3;
    const int c       = tid >> 2;
    const int w0      = quarter * 4;
    float4 o;
    o.x = sm[w0 + 0][c] * sml[w0 + 0];
    o.y = sm[w0 + 1][c] * sml[w0 + 1];
    o.z = sm[w0 + 2][c] * sml[w0 + 2];
    o.w = sm[w0 + 3][c] * sml[w0 + 3];
    *(float4*)(out + (((size_t)((b * NCH + c) * NLAT + ho)) << 8) + wo0 + w0) = o;
}

extern "C" void kernel_launch(void* const* d_in, const int* in_sizes, int n_in,
                              void* d_out, int out_size, void* d_ws, size_t ws_size,
                              hipStream_t stream) {
    const float* query = (const float*)d_in[0];
    const float* q_w   = (const float*)d_in[1];
    const float* k_w   = (const float*)d_in[2];
    const float* v_w   = (const float*)d_in[3];
    const float* q_b   = (const float*)d_in[4];
    const float* k_b   = (const float*)d_in[5];
    const float* v_b   = (const float*)d_in[6];
    const float* qwt   = (const float*)d_in[7];
    const int* psi_row = (const int*)d_in[8];
    const int* psi_col = (const int*)d_in[9];
    const int nnz      = in_sizes[8];

    char* ws = (char*)d_ws;
    unsigned short* qB = (unsigned short*)(ws);
    unsigned short* kB = (unsigned short*)(ws + 33554432);
    unsigned short* vB = (unsigned short*)(ws + 67108864);
    int* rp            = (int*)(ws + 100663296);

    k_rowptr<<<dim3(1), dim3(256), 0, stream>>>(psi_row, nnz, rp);
    k_qkv<<<dim3(1024, 3), dim3(256), 0, stream>>>(query, q_w, k_w, v_w, q_b, k_b, v_b, qB, kB, vB);
    k_attn<<<dim3(4096), dim3(1024), 0, stream>>>(qB, kB, vB, psi_col, qwt, rp, (float*)d_out);
}

// Round 3
// 1208.120 us; speedup vs baseline: 1.6385x; 1.6385x over previous
//
#include <hip/hip_runtime.h>
#include <hip/hip_bf16.h>
#include <cstdint>

// NeighborhoodAttentionS2: B=2, C=256, H=128, W=256
// Phase 1 (k_qkv): q/k = W@query (+bias) stored [b][h][w][c] bf16; v stored TRANSPOSED vT[b][h][c][w] bf16
// Phase 2 (k_attn): per (b,ho,wo-quarter) block, banded MFMA QK^T -> masked online softmax -> MFMA PV
// ws: qB[32MB] | kB[32MB] | vT[32MB] | rp[129]

#define NLAT 128
#define NLON 256
#define NCH  256
#define HWSZ (NLAT * NLON)
#define SEGN 11

typedef __attribute__((ext_vector_type(4))) float f32x4;
typedef __attribute__((ext_vector_type(8))) short s16x8;

__device__ __forceinline__ float bf2f(unsigned int hi_bits) {
    return __uint_as_float(hi_bits);
}
__device__ __forceinline__ unsigned short f2bf(float f) {
    unsigned int u = __float_as_uint(f);
    return (unsigned short)((u + 0x7fffu + ((u >> 16) & 1u)) >> 16);
}

// ---------------- CSR row pointers ----------------
__global__ void k_rowptr(const int* __restrict__ rows, int nnz, int* __restrict__ rp) {
    int ho = threadIdx.x;
    if (ho > NLAT) return;
    int lo = 0, hi = nnz;
    while (lo < hi) {
        int mid = (lo + hi) >> 1;
        if (rows[mid] < ho) lo = mid + 1; else hi = mid;
    }
    rp[ho] = lo;
}

// ---------------- QKV projection ----------------
__global__ __launch_bounds__(256) void k_qkv(
    const float* __restrict__ query,
    const float* __restrict__ qw, const float* __restrict__ kw, const float* __restrict__ vw,
    const float* __restrict__ qb, const float* __restrict__ kb, const float* __restrict__ vb,
    unsigned short* __restrict__ qB, unsigned short* __restrict__ kB, unsigned short* __restrict__ vT)
{
    const int y = blockIdx.y;
    const float* Wm; const float* bias; float scale;
    if (y == 0)      { Wm = qw; bias = qb; scale = 0.0625f; }
    else if (y == 1) { Wm = kw; bias = kb; scale = 1.0f; }
    else             { Wm = vw; bias = vb; scale = 1.0f; }

    __shared__ unsigned short As[256][40];
    __shared__ unsigned short Bs[64][40];

    const int n0  = blockIdx.x * 64;
    const int b   = n0 >> 15;
    const int hw0 = n0 & (HWSZ - 1);
    const float* qsrc = query + (size_t)b * NCH * HWSZ + hw0;

    const int tid  = threadIdx.x;
    const int lane = tid & 63;
    const int w    = tid >> 6;

    f32x4 acc[4][4] = {};

    const int la_m = tid >> 3;
    const int la_k = (tid & 7) * 4;
    const int lb_n = tid & 63;
    const int lb_k = tid >> 6;

    for (int ks = 0; ks < 8; ++ks) {
        const int k0 = ks * 32;
        #pragma unroll
        for (int r = 0; r < 8; ++r) {
            const int m = la_m + r * 32;
            const float4 v = *(const float4*)(Wm + (size_t)m * NCH + k0 + la_k);
            ushort4 st;
            st.x = f2bf(v.x * scale); st.y = f2bf(v.y * scale);
            st.z = f2bf(v.z * scale); st.w = f2bf(v.w * scale);
            *(ushort4*)&As[m][la_k] = st;
        }
        #pragma unroll
        for (int r = 0; r < 8; ++r) {
            const int kk = lb_k + r * 4;
            Bs[lb_n][kk] = f2bf(qsrc[(size_t)(k0 + kk) * HWSZ + lb_n]);
        }
        __syncthreads();

        s16x8 af[4], bfr[4];
        #pragma unroll
        for (int i = 0; i < 4; ++i)
            af[i] = *(const s16x8*)&As[w * 64 + i * 16 + (lane & 15)][(lane >> 4) * 8];
        #pragma unroll
        for (int j = 0; j < 4; ++j)
            bfr[j] = *(const s16x8*)&Bs[j * 16 + (lane & 15)][(lane >> 4) * 8];
        #pragma unroll
        for (int i = 0; i < 4; ++i)
            #pragma unroll
            for (int j = 0; j < 4; ++j)
                acc[i][j] = __builtin_amdgcn_mfma_f32_16x16x32_bf16(af[i], bfr[j], acc[i][j], 0, 0, 0);
        __syncthreads();
    }

    const int mrow = (lane >> 4) * 4;
    if (y == 2) {
        // transposed store: vT[((b*128 + h)*256 + m)*256 + wcol]
        const int h = hw0 >> 8;
        const int wbase = hw0 & 255;
        #pragma unroll
        for (int i = 0; i < 4; ++i) {
            const int m0 = w * 64 + i * 16 + mrow;
            const float4 bv = *(const float4*)(bias + m0);
            #pragma unroll
            for (int j = 0; j < 4; ++j) {
                const int wc = wbase + j * 16 + (lane & 15);
                const size_t rowb = ((size_t)((b * 128 + h) * 256 + m0)) << 8;
                vT[rowb + wc]                    = f2bf(acc[i][j][0] + bv.x);
                vT[rowb + 256 + wc]              = f2bf(acc[i][j][1] + bv.y);
                vT[rowb + 512 + wc]              = f2bf(acc[i][j][2] + bv.z);
                vT[rowb + 768 + wc]              = f2bf(acc[i][j][3] + bv.w);
            }
        }
    } else {
        unsigned short* outp = (y == 0) ? qB : kB;
        #pragma unroll
        for (int i = 0; i < 4; ++i) {
            const int m0 = w * 64 + i * 16 + mrow;
            const float4 bv = *(const float4*)(bias + m0);
            #pragma unroll
            for (int j = 0; j < 4; ++j) {
                const int n = j * 16 + (lane & 15);
                ushort4 st;
                st.x = f2bf(acc[i][j][0] + bv.x);
                st.y = f2bf(acc[i][j][1] + bv.y);
                st.z = f2bf(acc[i][j][2] + bv.z);
                st.w = f2bf(acc[i][j][3] + bv.w);
                *(ushort4*)(outp + (((size_t)(b * HWSZ + hw0 + n)) << 8) + m0) = st;
            }
        }
    }
}

// ---------------- banded MFMA neighborhood attention ----------------
// grid 1024 = (b2 x ho128 x woq4), XCD-swizzled. block 256 = 4 waves, wave owns 16 wo rows.
__global__ __launch_bounds__(256) void k_attn(
    const unsigned short* __restrict__ qB,
    const unsigned short* __restrict__ kB,
    const unsigned short* __restrict__ vT,
    const int* __restrict__ psi_col,
    const float* __restrict__ qwt,
    const int* __restrict__ rp,
    float* __restrict__ out)
{
    __shared__ __align__(16) unsigned char smem[68096];        // Ks(33280) + VTs(34816) | Osm(65536)
    unsigned short (*Ks)[260]  = (unsigned short(*)[260])smem;          // [j<64][c 256 pad260]
    unsigned short (*VTs)[68]  = (unsigned short(*)[68])(smem + 33280); // [c 256][j<64 pad68]
    float (*Osm)[64]           = (float(*)[64])smem;                    // [c 256][m 64]
    __shared__ unsigned short als[4][16][68];                           // per-wave alpha [m16][j<64 pad68]
    __shared__ unsigned int   segmask[SEGN][8];
    __shared__ int seg_dlo[SEGN], seg_ext[SEGN];

    const int bid  = blockIdx.x;
    const int orig = (bid & 7) * 128 + (bid >> 3);   // bijective XCD swizzle (1024 = 8*128)
    const int b    = orig >> 9;
    const int ho   = (orig >> 2) & 127;
    const int wo0  = (orig & 3) * 64;

    const int tid  = threadIdx.x;
    const int lane = tid & 63;
    const int wv   = tid >> 6;
    const int l15  = lane & 15;
    const int g    = lane >> 4;

    // ---- build per-(ho,hi) masks from CSR (exact validity) ----
    for (int i = tid; i < SEGN * 8; i += 256) ((unsigned*)segmask)[i] = 0u;
    __syncthreads();
    const int r0 = rp[ho], r1 = rp[ho + 1];
    for (int n = r0 + tid; n < r1; n += 256) {
        const int col = psi_col[n];
        const int s = (col >> 8) - ho + 5;
        if ((unsigned)s < SEGN) atomicOr(&segmask[s][(col & 255) >> 5], 1u << (col & 31));
    }
    __syncthreads();
    if (tid < SEGN) {
        const int hi = ho - 5 + tid;
        int dlo = 0, ext = 0;
        if (hi >= 0 && hi < 128) {
            unsigned mw[8]; int pc = 0;
            for (int w = 0; w < 8; ++w) { mw[w] = segmask[tid][w]; pc += __popc(mw[w]); }
            if (pc >= 256) { dlo = 0; ext = 256; }
            else if (pc > 0) {
                int t = 0; bool run = true;
                for (int w = 0; w < 8; ++w) {
                    if (!run) break;
                    if (mw[w] == 0xffffffffu) t += 32;
                    else { t += __ffs(~mw[w]) - 1; run = false; }
                }
                int z = 0; run = true;
                for (int w = 7; w >= 0; --w) {
                    if (!run) break;
                    if (mw[w] == 0xffffffffu) z += 32;
                    else { z += __clz(~mw[w]); run = false; }
                }
                if (pc == t + z && t + z <= 256) { dlo = -z; ext = pc; }
                else { dlo = 0; ext = 256; }   // fallback: stage everything, mask decides
            }
        }
        seg_dlo[tid] = dlo; seg_ext[tid] = ext;
    }
    __syncthreads();

    // ---- Q fragments (wave's 16 wo rows, full C=256) ----
    const size_t qpt = ((size_t)(b * HWSZ + ho * 256 + wo0 + wv * 16 + l15)) << 8;
    s16x8 af[8];
    #pragma unroll
    for (int ck = 0; ck < 8; ++ck) af[ck] = *(const s16x8*)(qB + qpt + ck * 32 + g * 8);

    f32x4 O[16] = {};
    float M[4] = {-1e38f, -1e38f, -1e38f, -1e38f};
    float L[4] = {0.f, 0.f, 0.f, 0.f};
    int mm[4];
    #pragma unroll
    for (int r = 0; r < 4; ++r) mm[r] = wv * 16 + 4 * g + r;

#define CHUNK_BODY(JT)                                                                      \
    {                                                                                       \
        f32x4 S[JT];                                                                        \
        _Pragma("unroll")                                                                   \
        for (int jt = 0; jt < JT; ++jt) {                                                   \
            f32x4 a = {};                                                                   \
            _Pragma("unroll")                                                               \
            for (int ck = 0; ck < 8; ++ck) {                                                \
                s16x8 bf = *(const s16x8*)&Ks[jt * 16 + l15][ck * 32 + g * 8];              \
                a = __builtin_amdgcn_mfma_f32_16x16x32_bf16(af[ck], bf, a, 0, 0, 0);        \
            }                                                                               \
            S[jt] = a;                                                                      \
        }                                                                                   \
        _Pragma("unroll")                                                                   \
        for (int jt = 0; jt < JT; ++jt) {                                                   \
            const int jj = j0 + jt * 16 + l15;                                              \
            _Pragma("unroll")                                                               \
            for (int r = 0; r < 4; ++r) {                                                   \
                const int wi = (jj - mm[r] + boff) & 255;                                   \
                const unsigned sel = (wi & 0x80)                                            \
                    ? ((wi & 0x40) ? ((wi & 0x20) ? mk7 : mk6) : ((wi & 0x20) ? mk5 : mk4)) \
                    : ((wi & 0x40) ? ((wi & 0x20) ? mk3 : mk2) : ((wi & 0x20) ? mk1 : mk0));\
                if (!((sel >> (wi & 31)) & 1u)) S[jt][r] = -3e38f;                          \
            }                                                                               \
        }                                                                                   \
        float rmax[4];                                                                      \
        _Pragma("unroll")                                                                   \
        for (int r = 0; r < 4; ++r) {                                                       \
            float v = S[0][r];                                                              \
            _Pragma("unroll")                                                               \
            for (int jt = 1; jt < JT; ++jt) v = fmaxf(v, S[jt][r]);                         \
            v = fmaxf(v, __shfl_xor(v, 1));                                                 \
            v = fmaxf(v, __shfl_xor(v, 2));                                                 \
            v = fmaxf(v, __shfl_xor(v, 4));                                                 \
            v = fmaxf(v, __shfl_xor(v, 8));                                                 \
            rmax[r] = v;                                                                    \
        }                                                                                   \
        _Pragma("unroll")                                                                   \
        for (int r = 0; r < 4; ++r) {                                                       \
            const float Mn = fmaxf(M[r], rmax[r]);                                          \
            const float f = __expf(M[r] - Mn);                                              \
            M[r] = Mn; L[r] *= f;                                                           \
            _Pragma("unroll")                                                               \
            for (int ct = 0; ct < 16; ++ct) O[ct][r] *= f;                                  \
        }                                                                                   \
        _Pragma("unroll")                                                                   \
        for (int jt = 0; jt < JT; ++jt) {                                                   \
            _Pragma("unroll")                                                               \
            for (int r = 0; r < 4; ++r) {                                                   \
                const float a = qw * __expf(S[jt][r] - M[r]);                               \
                const unsigned short ab = f2bf(a);                                          \
                L[r] += bf2f(((unsigned)ab) << 16);                                         \
                als[wv][4 * g + r][jt * 16 + l15] = ab;                                     \
            }                                                                               \
        }                                                                                   \
        _Pragma("unroll")                                                                   \
        for (int ck2 = 0; ck2 < JT / 2; ++ck2) {                                            \
            const s16x8 afr = *(const s16x8*)&als[wv][l15][ck2 * 32 + g * 8];               \
            _Pragma("unroll")                                                               \
            for (int ct = 0; ct < 16; ++ct) {                                               \
                s16x8 bf = *(const s16x8*)&VTs[ct * 16 + l15][ck2 * 32 + g * 8];            \
                O[ct] = __builtin_amdgcn_mfma_f32_16x16x32_bf16(afr, bf, O[ct], 0, 0, 0);   \
            }                                                                               \
        }                                                                                   \
    }

    for (int s = 0; s < SEGN; ++s) {
        const int ext = seg_ext[s];
        if (ext == 0) continue;
        const int dlo = seg_dlo[s];
        const int hi = ho - 5 + s;
        const float qw = qwt[hi];
        const unsigned mk0 = segmask[s][0], mk1 = segmask[s][1], mk2 = segmask[s][2], mk3 = segmask[s][3];
        const unsigned mk4 = segmask[s][4], mk5 = segmask[s][5], mk6 = segmask[s][6], mk7 = segmask[s][7];
        const int st   = wo0 + dlo;
        const int pad  = st & 31;
        const int base = (st - pad) & 255;          // 32-aligned window start
        int jtot = 63 + pad + ext; if (jtot > 256) jtot = 256;
        const int jt32 = (jtot + 31) & ~31;
        const int boff = (dlo - pad) & 255;
        const size_t kbase = ((size_t)(b * HWSZ + hi * 256)) << 8;
        const unsigned short* vrow = vT + (((size_t)((b * 128 + hi) * 256)) << 8);

        for (int j0 = 0; j0 < jt32; j0 += 64) {
            const int jcs = (jt32 - j0 >= 64) ? 64 : 32;
            const int abs0 = (base + j0) & 255;
            const int split = 256 - abs0;           // multiple of 32
            if (jcs == 64) {
                // K: 64 rows x 512B; thread: row=tid>>2, part=tid&3, 8x16B
                const int jrow = tid >> 2, part = tid & 3;
                const int acol = (abs0 + jrow) & 255;
                const unsigned short* src = kB + kbase + ((size_t)acol << 8);
                #pragma unroll
                for (int i = 0; i < 8; ++i) {
                    const int off = part * 8 + i * 32;
                    *(s16x8*)&Ks[jrow][off] = *(const s16x8*)(src + off);
                }
                // VT: 256 rows x 128B; 4 passes, row=pass*64+(tid>>2), 2x16B
                #pragma unroll
                for (int pass = 0; pass < 4; ++pass) {
                    const int c = pass * 64 + (tid >> 2);
                    const unsigned short* vr = vrow + ((size_t)c << 8);
                    #pragma unroll
                    for (int i = 0; i < 2; ++i) {
                        const int jj8 = (tid & 3) * 8 + i * 32;
                        const int sc = (jj8 < split) ? (abs0 + jj8) : (jj8 - split);
                        *(s16x8*)&VTs[c][jj8] = *(const s16x8*)(vr + sc);
                    }
                }
            } else {
                const int jrow = tid >> 3, part = tid & 7;
                const int acol = (abs0 + jrow) & 255;
                const unsigned short* src = kB + kbase + ((size_t)acol << 8);
                #pragma unroll
                for (int i = 0; i < 4; ++i) {
                    const int off = part * 8 + i * 64;
                    *(s16x8*)&Ks[jrow][off] = *(const s16x8*)(src + off);
                }
                #pragma unroll
                for (int pass = 0; pass < 4; ++pass) {
                    const int c = pass * 64 + (tid >> 2);
                    const unsigned short* vr = vrow + ((size_t)c << 8);
                    const int jj8 = (tid & 3) * 8;
                    const int sc = (jj8 < split) ? (abs0 + jj8) : (jj8 - split);
                    *(s16x8*)&VTs[c][jj8] = *(const s16x8*)(vr + sc);
                }
            }
            __syncthreads();
            if (jcs == 64) CHUNK_BODY(4) else CHUNK_BODY(2)
            __syncthreads();
        }
    }
#undef CHUNK_BODY

    // ---- finalize: L-reduce, scale, transpose via LDS, coalesced write ----
    float rL[4];
    #pragma unroll
    for (int r = 0; r < 4; ++r) {
        float v = L[r];
        v += __shfl_xor(v, 1);
        v += __shfl_xor(v, 2);
        v += __shfl_xor(v, 4);
        v += __shfl_xor(v, 8);
        rL[r] = 1.0f / v;
    }
    #pragma unroll
    for (int ct = 0; ct < 16; ++ct) {
        #pragma unroll
        for (int r = 0; r < 4; ++r)
            Osm[ct * 16 + l15][wv * 16 + 4 * g + r] = O[ct][r] * rL[r];
    }
    __syncthreads();
    const int m4 = (tid & 15) * 4;
    #pragma unroll
    for (int ci = 0; ci < 16; ++ci) {
        const int c = ci * 16 + (tid >> 4);
        const f32x4 o = *(const f32x4*)&Osm[c][m4];
        *(f32x4*)(out + (((size_t)((b * NCH + c) * NLAT + ho)) << 8) + wo0 + m4) = o;
    }
}

extern "C" void kernel_launch(void* const* d_in, const int* in_sizes, int n_in,
                              void* d_out, int out_size, void* d_ws, size_t ws_size,
                              hipStream_t stream) {
    const float* query = (const float*)d_in[0];
    const float* q_w   = (const float*)d_in[1];
    const float* k_w   = (const float*)d_in[2];
    const float* v_w   = (const float*)d_in[3];
    const float* q_b   = (const float*)d_in[4];
    const float* k_b   = (const float*)d_in[5];
    const float* v_b   = (const float*)d_in[6];
    const float* qwt   = (const float*)d_in[7];
    const int* psi_row = (const int*)d_in[8];
    const int* psi_col = (const int*)d_in[9];
    const int nnz      = in_sizes[8];

    char* ws = (char*)d_ws;
    unsigned short* qB = (unsigned short*)(ws);
    unsigned short* kB = (unsigned short*)(ws + 33554432);
    unsigned short* vT = (unsigned short*)(ws + 67108864);
    int* rp            = (int*)(ws + 100663296);

    k_rowptr<<<dim3(1), dim3(256), 0, stream>>>(psi_row, nnz, rp);
    k_qkv<<<dim3(1024, 3), dim3(256), 0, stream>>>(query, q_w, k_w, v_w, q_b, k_b, v_b, qB, kB, vT);
    k_attn<<<dim3(1024), dim3(256), 0, stream>>>(qB, kB, vT, psi_col, qwt, rp, (float*)d_out);
}

// Round 4
// 643.022 us; speedup vs baseline: 3.0785x; 1.8788x over previous
//
#include <hip/hip_runtime.h>
#include <hip/hip_bf16.h>
#include <cstdint>

// NeighborhoodAttentionS2: B=2, C=256, H=128, W=256
// k_qkv (fused): q/k = W@query (+bias) -> [b][hw][c] bf16; v -> TRANSPOSED vT[b][h][c][w] bf16
// k_attn: per (b,ho,quarter) block, 4 independent waves each own a 16-wo strip.
//   QK^T and PV MFMA read K/V fragments DIRECTLY from global (L2-resident, no staging,
//   no block barriers in main loop). Masked online softmax w/ defer-max (THR=8).
// ws: qB[32MB] | kB[32MB] | vT[32MB] | rp[129]

#define NLAT 128
#define NLON 256
#define NCH  256
#define HWSZ (NLAT * NLON)
#define SEGN 11

typedef __attribute__((ext_vector_type(4))) float f32x4;
typedef __attribute__((ext_vector_type(8))) short s16x8;

__device__ __forceinline__ float bf2f(unsigned int hi_bits) {
    return __uint_as_float(hi_bits);
}
__device__ __forceinline__ unsigned short f2bf(float f) {
    unsigned int u = __float_as_uint(f);
    return (unsigned short)((u + 0x7fffu + ((u >> 16) & 1u)) >> 16);
}

// ---------------- CSR row pointers ----------------
__global__ void k_rowptr(const int* __restrict__ rows, int nnz, int* __restrict__ rp) {
    int ho = threadIdx.x;
    if (ho > NLAT) return;
    int lo = 0, hi = nnz;
    while (lo < hi) {
        int mid = (lo + hi) >> 1;
        if (rows[mid] < ho) lo = mid + 1; else hi = mid;
    }
    rp[ho] = lo;
}

// ---------------- fused QKV projection ----------------
// grid 1024, block 256. Block: 64 points, query staged to LDS ONCE, then y=0..2 GEMMs.
__global__ __launch_bounds__(256) void k_qkv(
    const float* __restrict__ query,
    const float* __restrict__ qw, const float* __restrict__ kw, const float* __restrict__ vw,
    const float* __restrict__ qb, const float* __restrict__ kb, const float* __restrict__ vb,
    unsigned short* __restrict__ qB, unsigned short* __restrict__ kB, unsigned short* __restrict__ vT)
{
    __shared__ unsigned short As[256][40];   // weight slice [m][k32]
    __shared__ unsigned short Bs[64][264];   // query [n][k256], 528B rows (16B-mult)

    const int n0  = blockIdx.x * 64;
    const int b   = n0 >> 15;
    const int hw0 = n0 & (HWSZ - 1);
    const float* qsrc = query + (size_t)b * NCH * HWSZ + hw0;

    const int tid  = threadIdx.x;
    const int lane = tid & 63;
    const int w    = tid >> 6;
    const int l15  = lane & 15;
    const int g    = lane >> 4;

    // stage full query tile once (read 1x instead of 3x)
    {
        const int n   = tid & 63;
        const int k0r = tid >> 6;
        #pragma unroll 8
        for (int it = 0; it < 64; ++it) {
            const int kk = k0r + it * 4;
            Bs[n][kk] = f2bf(qsrc[(size_t)kk * HWSZ + n]);
        }
    }

    const int la_m = tid >> 3;
    const int la_k = (tid & 7) * 4;

    for (int y = 0; y < 3; ++y) {
        const float* Wm; const float* bias; float scale;
        if (y == 0)      { Wm = qw; bias = qb; scale = 0.0625f; }
        else if (y == 1) { Wm = kw; bias = kb; scale = 1.0f; }
        else             { Wm = vw; bias = vb; scale = 1.0f; }

        f32x4 acc[4][4] = {};

        for (int ks = 0; ks < 8; ++ks) {
            const int k0 = ks * 32;
            __syncthreads();             // As readers of prev slice done / Bs staged
            #pragma unroll
            for (int r = 0; r < 8; ++r) {
                const int m = la_m + r * 32;
                const float4 v = *(const float4*)(Wm + (size_t)m * NCH + k0 + la_k);
                ushort4 st;
                st.x = f2bf(v.x * scale); st.y = f2bf(v.y * scale);
                st.z = f2bf(v.z * scale); st.w = f2bf(v.w * scale);
                *(ushort4*)&As[m][la_k] = st;
            }
            __syncthreads();

            s16x8 af[4], bfr[4];
            #pragma unroll
            for (int i = 0; i < 4; ++i)
                af[i] = *(const s16x8*)&As[w * 64 + i * 16 + l15][g * 8];
            #pragma unroll
            for (int j = 0; j < 4; ++j)
                bfr[j] = *(const s16x8*)&Bs[j * 16 + l15][k0 + g * 8];
            #pragma unroll
            for (int i = 0; i < 4; ++i)
                #pragma unroll
                for (int j = 0; j < 4; ++j)
                    acc[i][j] = __builtin_amdgcn_mfma_f32_16x16x32_bf16(af[i], bfr[j], acc[i][j], 0, 0, 0);
        }

        const int mrow = (g) * 4;
        if (y == 2) {
            const int h = hw0 >> 8;
            const int wbase = hw0 & 255;
            #pragma unroll
            for (int i = 0; i < 4; ++i) {
                const int m0 = w * 64 + i * 16 + mrow;
                const float4 bv = *(const float4*)(bias + m0);
                #pragma unroll
                for (int j = 0; j < 4; ++j) {
                    const int wc = wbase + j * 16 + l15;
                    const size_t rowb = ((size_t)((b * 128 + h) * 256 + m0)) << 8;
                    vT[rowb + wc]       = f2bf(acc[i][j][0] + bv.x);
                    vT[rowb + 256 + wc] = f2bf(acc[i][j][1] + bv.y);
                    vT[rowb + 512 + wc] = f2bf(acc[i][j][2] + bv.z);
                    vT[rowb + 768 + wc] = f2bf(acc[i][j][3] + bv.w);
                }
            }
        } else {
            unsigned short* outp = (y == 0) ? qB : kB;
            #pragma unroll
            for (int i = 0; i < 4; ++i) {
                const int m0 = w * 64 + i * 16 + mrow;
                const float4 bv = *(const float4*)(bias + m0);
                #pragma unroll
                for (int j = 0; j < 4; ++j) {
                    const int n = j * 16 + l15;
                    ushort4 st;
                    st.x = f2bf(acc[i][j][0] + bv.x);
                    st.y = f2bf(acc[i][j][1] + bv.y);
                    st.z = f2bf(acc[i][j][2] + bv.z);
                    st.w = f2bf(acc[i][j][3] + bv.w);
                    *(ushort4*)(outp + (((size_t)(b * HWSZ + hw0 + n)) << 8) + m0) = st;
                }
            }
        }
    }
}

// ---------------- direct-from-L2 MFMA neighborhood attention ----------------
// grid 1024 = (b2 x ho128 x quarter4), XCD-swizzled. block 256 = 4 waves.
// Each wave owns a 16-wo strip; main loop has NO block barriers.
__global__ __launch_bounds__(256, 2) void k_attn(
    const unsigned short* __restrict__ qB,
    const unsigned short* __restrict__ kB,
    const unsigned short* __restrict__ vT,
    const int* __restrict__ psi_col,
    const float* __restrict__ qwt,
    const int* __restrict__ rp,
    float* __restrict__ out)
{
    __shared__ unsigned int   segmask[SEGN][8];
    __shared__ int seg_dlo[SEGN], seg_ext[SEGN];
    __shared__ unsigned short als[4][16][40];   // per-wave alpha [m16][j32 pad40], 80B rows
    __shared__ float Osm[128][68];              // output transpose (half-C pass)

    const int bid  = blockIdx.x;
    const int orig = (bid & 7) * 128 + (bid >> 3);   // bijective XCD swizzle
    const int b    = orig >> 9;
    const int ho   = (orig >> 2) & 127;
    const int wo0  = (orig & 3) * 64;

    const int tid  = threadIdx.x;
    const int lane = tid & 63;
    const int wv   = tid >> 6;
    const int l15  = lane & 15;
    const int g    = lane >> 4;

    // ---- build per-(ho,hi) masks from CSR (exact validity) ----
    for (int i = tid; i < SEGN * 8; i += 256) ((unsigned*)segmask)[i] = 0u;
    __syncthreads();
    const int r0 = rp[ho], r1 = rp[ho + 1];
    for (int n = r0 + tid; n < r1; n += 256) {
        const int col = psi_col[n];
        const int s = (col >> 8) - ho + 5;
        if ((unsigned)s < SEGN) atomicOr(&segmask[s][(col & 255) >> 5], 1u << (col & 31));
    }
    __syncthreads();
    if (tid < SEGN) {
        const int hi = ho - 5 + tid;
        int dlo = 0, ext = 0;
        if (hi >= 0 && hi < 128) {
            unsigned mw[8]; int pc = 0;
            for (int w = 0; w < 8; ++w) { mw[w] = segmask[tid][w]; pc += __popc(mw[w]); }
            if (pc >= 256) { dlo = 0; ext = 256; }
            else if (pc > 0) {
                int t = 0; bool run = true;
                for (int w = 0; w < 8; ++w) {
                    if (!run) break;
                    if (mw[w] == 0xffffffffu) t += 32;
                    else { t += __ffs(~mw[w]) - 1; run = false; }
                }
                int z = 0; run = true;
                for (int w = 7; w >= 0; --w) {
                    if (!run) break;
                    if (mw[w] == 0xffffffffu) z += 32;
                    else { z += __clz(~mw[w]); run = false; }
                }
                if (pc == t + z && t + z <= 256) { dlo = -z; ext = pc; }
                else { dlo = 0; ext = 256; }   // fallback: full window, mask decides
            }
        }
        seg_dlo[tid] = dlo; seg_ext[tid] = ext;
    }
    __syncthreads();

    // ---- wave-private strip ----
    const int ws0 = wo0 + wv * 16;
    const size_t qpt = ((size_t)(b * HWSZ + ho * 256 + ws0 + l15)) << 8;
    s16x8 af[8];
    #pragma unroll
    for (int ck = 0; ck < 8; ++ck) af[ck] = *(const s16x8*)(qB + qpt + ck * 32 + g * 8);

    f32x4 O[16] = {};
    float M[4] = {-1e38f, -1e38f, -1e38f, -1e38f};
    float L[4] = {0.f, 0.f, 0.f, 0.f};

    const size_t kbb = ((size_t)(b * HWSZ)) << 8;
    const unsigned short* vbb = vT + (((size_t)(b * 128)) << 8) * 256;

    for (int s = 0; s < SEGN; ++s) {
        const int ext = seg_ext[s];
        if (ext == 0) continue;
        const int dlo = seg_dlo[s];
        const int hi  = ho - 5 + s;
        const float qw = qwt[hi];
        const unsigned mk0 = __builtin_amdgcn_readfirstlane(segmask[s][0]);
        const unsigned mk1 = __builtin_amdgcn_readfirstlane(segmask[s][1]);
        const unsigned mk2 = __builtin_amdgcn_readfirstlane(segmask[s][2]);
        const unsigned mk3 = __builtin_amdgcn_readfirstlane(segmask[s][3]);
        const unsigned mk4 = __builtin_amdgcn_readfirstlane(segmask[s][4]);
        const unsigned mk5 = __builtin_amdgcn_readfirstlane(segmask[s][5]);
        const unsigned mk6 = __builtin_amdgcn_readfirstlane(segmask[s][6]);
        const unsigned mk7 = __builtin_amdgcn_readfirstlane(segmask[s][7]);

        const int dlo8 = dlo & ~7;            // floor to mult of 8 (16B V alignment)
        const int pad  = dlo - dlo8;
        int jtot = 15 + pad + ext; if (jtot > 256) jtot = 256;
        const int wbase = (ws0 + dlo8) & 255;
        const unsigned short* kptr = kB + kbb + (((size_t)(hi * 256)) << 8);
        const unsigned short* vptr = vbb + (((size_t)(hi * 256)) << 8);

        for (int j0 = 0; j0 < jtot; j0 += 32) {
            // ---- QK^T: B-fragments direct from global ----
            f32x4 S[2];
            __builtin_amdgcn_s_setprio(1);
            #pragma unroll
            for (int jt = 0; jt < 2; ++jt) {
                const int wil = (wbase + j0 + jt * 16 + l15) & 255;
                const unsigned short* kp = kptr + (((size_t)wil) << 8) + g * 8;
                f32x4 a = {};
                #pragma unroll
                for (int ck = 0; ck < 8; ++ck) {
                    const s16x8 bf = *(const s16x8*)(kp + ck * 32);
                    a = __builtin_amdgcn_mfma_f32_16x16x32_bf16(af[ck], bf, a, 0, 0, 0);
                }
                S[jt] = a;
            }
            __builtin_amdgcn_s_setprio(0);

            // ---- exact mask ----
            #pragma unroll
            for (int jt = 0; jt < 2; ++jt) {
                const int tbase = dlo8 + j0 + jt * 16 + l15 - 4 * g;
                #pragma unroll
                for (int r = 0; r < 4; ++r) {
                    const int wi = (tbase - r) & 255;
                    const unsigned sel = (wi & 0x80)
                        ? ((wi & 0x40) ? ((wi & 0x20) ? mk7 : mk6) : ((wi & 0x20) ? mk5 : mk4))
                        : ((wi & 0x40) ? ((wi & 0x20) ? mk3 : mk2) : ((wi & 0x20) ? mk1 : mk0));
                    if (!((sel >> (wi & 31)) & 1u)) S[jt][r] = -3e38f;
                }
            }

            // ---- row max (16-lane groups) + defer-max ----
            float rmax[4];
            #pragma unroll
            for (int r = 0; r < 4; ++r) {
                float v = fmaxf(S[0][r], S[1][r]);
                v = fmaxf(v, __shfl_xor(v, 1));
                v = fmaxf(v, __shfl_xor(v, 2));
                v = fmaxf(v, __shfl_xor(v, 4));
                v = fmaxf(v, __shfl_xor(v, 8));
                rmax[r] = v;
            }
            int need = 0;
            #pragma unroll
            for (int r = 0; r < 4; ++r) need |= (rmax[r] > M[r] + 8.0f) ? 1 : 0;
            if (__any(need)) {
                #pragma unroll
                for (int r = 0; r < 4; ++r) {
                    const float Mn = fmaxf(M[r], rmax[r]);
                    const float f = __expf(M[r] - Mn);
                    M[r] = Mn; L[r] *= f;
                    #pragma unroll
                    for (int ct = 0; ct < 16; ++ct) O[ct][r] *= f;
                }
            }

            // ---- alpha (bf16), wave-private LDS transpose ----
            #pragma unroll
            for (int jt = 0; jt < 2; ++jt) {
                #pragma unroll
                for (int r = 0; r < 4; ++r) {
                    const float a = qw * __expf(S[jt][r] - M[r]);
                    const unsigned short ab = f2bf(a);
                    L[r] += bf2f(((unsigned)ab) << 16);
                    als[wv][4 * g + r][jt * 16 + l15] = ab;
                }
            }
            const s16x8 afr = *(const s16x8*)&als[wv][l15][g * 8];

            // ---- PV: B-fragments direct from global vT ----
            const int wj = (wbase + j0 + g * 8) & 255;    // mult of 8 -> 16B aligned, no row cross
            __builtin_amdgcn_s_setprio(1);
            #pragma unroll
            for (int ct = 0; ct < 16; ++ct) {
                const s16x8 vb8 = *(const s16x8*)(vptr + (((size_t)(ct * 16 + l15)) << 8) + wj);
                O[ct] = __builtin_amdgcn_mfma_f32_16x16x32_bf16(afr, vb8, O[ct], 0, 0, 0);
            }
            __builtin_amdgcn_s_setprio(0);
        }
    }

    // ---- finalize ----
    float rL[4];
    #pragma unroll
    for (int r = 0; r < 4; ++r) {
        float v = L[r];
        v += __shfl_xor(v, 1);
        v += __shfl_xor(v, 2);
        v += __shfl_xor(v, 4);
        v += __shfl_xor(v, 8);
        rL[r] = 1.0f / v;
    }
    __syncthreads();   // all waves done with als before Osm reuse pattern begins
    #pragma unroll
    for (int p = 0; p < 2; ++p) {
        #pragma unroll
        for (int ci = 0; ci < 8; ++ci) {
            const int ct = p * 8 + ci;
            #pragma unroll
            for (int r = 0; r < 4; ++r)
                Osm[ci * 16 + l15][wv * 16 + 4 * g + r] = O[ct][r] * rL[r];
        }
        __syncthreads();
        const int m4 = (tid & 15) * 4;
        #pragma unroll
        for (int ci = 0; ci < 8; ++ci) {
            const int crow = ci * 16 + (tid >> 4);
            const int c = p * 128 + crow;
            const f32x4 o = *(const f32x4*)&Osm[crow][m4];
            *(f32x4*)(out + (((size_t)((b * NCH + c) * NLAT + ho)) << 8) + wo0 + m4) = o;
        }
        __syncthreads();
    }
}

extern "C" void kernel_launch(void* const* d_in, const int* in_sizes, int n_in,
                              void* d_out, int out_size, void* d_ws, size_t ws_size,
                              hipStream_t stream) {
    const float* query = (const float*)d_in[0];
    const float* q_w   = (const float*)d_in[1];
    const float* k_w   = (const float*)d_in[2];
    const float* v_w   = (const float*)d_in[3];
    const float* q_b   = (const float*)d_in[4];
    const float* k_b   = (const float*)d_in[5];
    const float* v_b   = (const float*)d_in[6];
    const float* qwt   = (const float*)d_in[7];
    const int* psi_row = (const int*)d_in[8];
    const int* psi_col = (const int*)d_in[9];
    const int nnz      = in_sizes[8];

    char* ws = (char*)d_ws;
    unsigned short* qB = (unsigned short*)(ws);
    unsigned short* kB = (unsigned short*)(ws + 33554432);
    unsigned short* vT = (unsigned short*)(ws + 67108864);
    int* rp            = (int*)(ws + 100663296);

    k_rowptr<<<dim3(1), dim3(256), 0, stream>>>(psi_row, nnz, rp);
    k_qkv<<<dim3(1024), dim3(256), 0, stream>>>(query, q_w, k_w, v_w, q_b, k_b, v_b, qB, kB, vT);
    k_attn<<<dim3(1024), dim3(256), 0, stream>>>(qB, kB, vT, psi_col, qwt, rp, (float*)d_out);
}